// Round 5
// baseline (989.633 us; speedup 1.0000x reference)
//
#include <hip/hip_runtime.h>
#include <stdint.h>

#define T_STEPS 300
#define T4 75

typedef __attribute__((ext_vector_type(8))) short bf16x8;
typedef __attribute__((ext_vector_type(4))) float f32x4;

// ---- scan (psp + spike) constants: d = exp(-1), c = e, cr = -2*theta*e ----
__device__ __forceinline__ void scan_step(float x, float& pp, float& pq,
                                          float& rp, float& rq, float& s_out) {
    const float D  = 0.36787944117144233f;
    const float C  = 2.7182818284590452f;
    const float CR = -54.365636569180904f;
    const float TH = 10.0f;
    pq = D * (pq + pp);      // psp state (q uses old p)
    pp = D * pp + x;
    float u = C * pq;
    rq = D * (rq + rp);      // refractory state
    float s = (u + CR * rq >= TH) ? 1.0f : 0.0f;
    rp = D * rp + s;
    s_out = s;
}

#define SCAN4(v, PACK)                                                     \
    {                                                                      \
        float s0, s1, s2, s3;                                              \
        scan_step(v.x, pp, pq, rp, rq, s0);                                \
        scan_step(v.y, pp, pq, rp, rq, s1);                                \
        scan_step(v.z, pp, pq, rp, rq, s2);                                \
        scan_step(v.w, pp, pq, rp, rq, s3);                                \
        PACK = (uint32_t)s0 | ((uint32_t)s1 << 8) |                        \
               ((uint32_t)s2 << 16) | ((uint32_t)s3 << 24);                \
    }

#define FMA4(A, wc) A.x = fmaf(wc, f0, A.x); A.y = fmaf(wc, f1, A.y); \
                    A.z = fmaf(wc, f2, A.z); A.w = fmaf(wc, f3, A.w);

// ---- SP0 spatial: 4x4 sum-pool * 11 on raw input (t-major z out) ----
__global__ __launch_bounds__(256) void k_pool4(const float* __restrict__ in,
                                               float* __restrict__ z) {
    int idx = blockIdx.x * 256 + threadIdx.x;   // 16384 * 75
    int t4 = idx % T4;
    int n  = idx / T4;                // (b*2+c)*1024 + y*32 + x
    int x = n & 31, y = (n >> 5) & 31, bc = n >> 10;
    const float* base = in + ((size_t)bc * 16384 + (size_t)(4 * y) * 128 + 4 * x) * T_STEPS + 4 * t4;
    float4 acc = {0.f, 0.f, 0.f, 0.f};
#pragma unroll
    for (int i = 0; i < 4; ++i)
#pragma unroll
        for (int j = 0; j < 4; ++j) {
            float4 v = *reinterpret_cast<const float4*>(base + ((size_t)i * 128 + j) * T_STEPS);
            acc.x += v.x; acc.y += v.y; acc.z += v.z; acc.w += v.w;
        }
    float4 o = {11.f * acc.x, 11.f * acc.y, 11.f * acc.z, 11.f * acc.w};
    *reinterpret_cast<float4*>(z + (size_t)n * T_STEPS + 4 * t4) = o;
}

// ---- scan: t-major f32 z in -> u32 spike planes out ----
__global__ __launch_bounds__(256) void k_scan_l0(const float* __restrict__ z,
                                                 uint32_t* __restrict__ sp, int N) {
    int n = blockIdx.x * 256 + threadIdx.x;
    if (n >= N) return;
    const float4* zp = reinterpret_cast<const float4*>(z + (size_t)n * T_STEPS);
    float pp = 0.f, pq = 0.f, rp = 0.f, rq = 0.f;
#pragma unroll 2
    for (int t4 = 0; t4 < T4; ++t4) {
        float4 v = zp[t4];
        uint32_t pack;
        SCAN4(v, pack);
        sp[(size_t)t4 * N + n] = pack;
    }
}

// ---- scan: f4 z planes in -> u32 spike planes out ----
__global__ __launch_bounds__(256) void k_scan_plane(const float4* __restrict__ z,
                                                    uint32_t* __restrict__ sp, int N) {
    int n = blockIdx.x * 256 + threadIdx.x;
    if (n >= N) return;
    float pp = 0.f, pq = 0.f, rp = 0.f, rq = 0.f;
#pragma unroll 2
    for (int t4 = 0; t4 < T4; ++t4) {
        float4 v = z[(size_t)t4 * N + n];
        uint32_t pack;
        SCAN4(v, pack);
        sp[(size_t)t4 * N + n] = pack;
    }
}

// ---- scan: t-major f32 z in -> t-major f32 spikes out (FC tail) ----
__global__ __launch_bounds__(256) void k_scan_f32(const float* __restrict__ z,
                                                  float* __restrict__ s, int N, int ostride) {
    int n = blockIdx.x * blockDim.x + threadIdx.x;
    if (n >= N) return;
    const float4* zp = reinterpret_cast<const float4*>(z + (size_t)n * T_STEPS);
    float* spo = s + (size_t)n * ostride;
    float pp = 0.f, pq = 0.f, rp = 0.f, rq = 0.f;
    for (int it = 0; it < T4; ++it) {
        float4 v = zp[it];
        float4 o;
        scan_step(v.x, pp, pq, rp, rq, o.x);
        scan_step(v.y, pp, pq, rp, rq, o.y);
        scan_step(v.z, pp, pq, rp, rq, o.z);
        scan_step(v.w, pp, pq, rp, rq, o.w);
        *reinterpret_cast<float4*>(spo + it * 4) = o;
    }
}

// ---- fused 2x2 sum-pool * 11 + scan on u32 spike planes (SP1) ----
template<int HW, int NIN, int NOUT>
__global__ __launch_bounds__(256) void k_pool2s(const uint32_t* __restrict__ sin,
                                                uint32_t* __restrict__ sout) {
    int n = blockIdx.x * 256 + threadIdx.x;
    if (n >= NOUT) return;
    int x = n % HW, y = (n / HW) % HW, bc = n / (HW * HW);
    const int W2d = HW * 2;
    const uint32_t* base0 = sin + (size_t)bc * W2d * W2d + (size_t)(2 * y) * W2d + 2 * x;
    float pp = 0.f, pq = 0.f, rp = 0.f, rq = 0.f;
#pragma unroll 2
    for (int t4 = 0; t4 < T4; ++t4) {
        const uint32_t* p = base0 + (size_t)t4 * NIN;
        uint32_t sum = p[0] + p[1] + p[W2d] + p[W2d + 1];  // SWAR, bytes <= 4
        float4 v;
        v.x = 11.f * (float)(sum & 0xffu);
        v.y = 11.f * (float)((sum >> 8) & 0xffu);
        v.z = 11.f * (float)((sum >> 16) & 0xffu);
        v.w = 11.f * (float)(sum >> 24);
        uint32_t pack;
        SCAN4(v, pack);
        sout[(size_t)t4 * NOUT + n] = pack;
    }
}

// ---- SP2: fused 2x2 pool + scan, emits k-major bf16 spikes [b][t_pad=320][2048] ----
__global__ __launch_bounds__(256) void k_pool2s_bf(const uint32_t* __restrict__ sin,
                                                   ushort* __restrict__ sb) {
    int n = blockIdx.x * 256 + threadIdx.x;   // 16384 = b*2048 + k (k = c*64+y*8+x)
    if (n >= 16384) return;
    int x = n & 7, y = (n >> 3) & 7, bc = n >> 6;
    const uint32_t* base0 = sin + (size_t)bc * 256 + (size_t)(2 * y) * 16 + 2 * x;
    int b = n >> 11, k = n & 2047;
    ushort* out = sb + (size_t)b * 320 * 2048 + k;
    float pp = 0.f, pq = 0.f, rp = 0.f, rq = 0.f;
    for (int t4 = 0; t4 < T4; ++t4) {
        const uint32_t* p = base0 + (size_t)t4 * 65536;
        uint32_t sum = p[0] + p[1] + p[16] + p[17];
        float4 v;
        v.x = 11.f * (float)(sum & 0xffu);
        v.y = 11.f * (float)((sum >> 8) & 0xffu);
        v.z = 11.f * (float)((sum >> 16) & 0xffu);
        v.w = 11.f * (float)(sum >> 24);
        float s0, s1, s2, s3;
        scan_step(v.x, pp, pq, rp, rq, s0);
        scan_step(v.y, pp, pq, rp, rq, s1);
        scan_step(v.z, pp, pq, rp, rq, s2);
        scan_step(v.w, pp, pq, rp, rq, s3);
        out[(size_t)(t4 * 4 + 0) * 2048] = s0 != 0.f ? 0x3F80 : 0;
        out[(size_t)(t4 * 4 + 1) * 2048] = s1 != 0.f ? 0x3F80 : 0;
        out[(size_t)(t4 * 4 + 2) * 2048] = s2 != 0.f ? 0x3F80 : 0;
        out[(size_t)(t4 * 4 + 3) * 2048] = s3 != 0.f ? 0x3F80 : 0;
    }
}

// ---- SC1: 5x5 conv 2->16 over 32x32; thread = (b,pix,t4), ALL 16 o in regs ----
__global__ __launch_bounds__(256) void k_conv1(const uint32_t* __restrict__ s0p,
                                               const float* __restrict__ W1,
                                               float4* __restrict__ z1p) {
    __shared__ float w_lds[2][25][16];
    int bid = blockIdx.x;               // 2400
    int pixblk = bid & 3;
    int t4 = (bid >> 2) % 75;
    int b  = bid / 300;
    int tid = threadIdx.x;
    for (int j = tid; j < 800; j += 256) {
        int o = j & 15, kk = (j >> 4) % 25, c = j / 400;
        w_lds[c][kk][o] = W1[(o * 2 + c) * 25 + kk];
    }
    __syncthreads();
    int pix = pixblk * 256 + tid;
    int px = pix & 31, py = pix >> 5;
    float4 acc[16];
#pragma unroll
    for (int o = 0; o < 16; ++o) acc[o] = make_float4(0.f, 0.f, 0.f, 0.f);
    const uint32_t* pb = s0p + (size_t)t4 * 16384 + (size_t)(b * 2) * 1024;
    for (int c = 0; c < 2; ++c) {
#pragma unroll
        for (int ky = 0; ky < 5; ++ky) {
            int yy = py + ky - 2;
            bool rok = (unsigned)yy < 32u;
#pragma unroll
            for (int kx = 0; kx < 5; ++kx) {
                int xx = px + kx - 2;
                uint32_t v = 0;
                if (rok && (unsigned)xx < 32u) v = pb[c * 1024 + yy * 32 + xx];
                float f0 = (float)(v & 0xffu), f1 = (float)((v >> 8) & 0xffu);
                float f2 = (float)((v >> 16) & 0xffu), f3 = (float)(v >> 24);
                int kk = ky * 5 + kx;
#pragma unroll
                for (int oo = 0; oo < 4; ++oo) {
                    float4 w4 = *reinterpret_cast<const float4*>(&w_lds[c][kk][oo * 4]);
                    FMA4(acc[oo * 4 + 0], w4.x);
                    FMA4(acc[oo * 4 + 1], w4.y);
                    FMA4(acc[oo * 4 + 2], w4.z);
                    FMA4(acc[oo * 4 + 3], w4.w);
                }
            }
        }
    }
    size_t zb = (size_t)t4 * 131072 + (size_t)(b * 16) * 1024 + pix;
#pragma unroll
    for (int o = 0; o < 16; ++o) z1p[zb + o * 1024] = acc[o];
}

// ---- SC2: 3x3 conv 16->32 over 16x16; thread = (b,pix,t4), 16 o per half ----
__global__ __launch_bounds__(256) void k_conv2(const uint32_t* __restrict__ s2p,
                                               const float* __restrict__ W2,
                                               float4* __restrict__ z2p) {
    __shared__ float w_lds[16][9][16];
    int bid = blockIdx.x;               // 1200
    int oh = bid & 1;
    int t4 = (bid >> 1) % 75;
    int b  = bid / 150;
    int tid = threadIdx.x;              // pix (16x16)
    for (int j = tid; j < 2304; j += 256) {
        int o = j & 15;
        int t9 = (j >> 4) % 9;
        int c  = j / 144;
        w_lds[c][t9][o] = W2[(size_t)((oh * 16 + o) * 16 + c) * 9 + t9];
    }
    __syncthreads();
    int px = tid & 15, py = tid >> 4;
    float4 acc[16];
#pragma unroll
    for (int o = 0; o < 16; ++o) acc[o] = make_float4(0.f, 0.f, 0.f, 0.f);
    const uint32_t* pb = s2p + (size_t)t4 * 32768 + (size_t)(b * 16) * 256;
    for (int c = 0; c < 16; ++c) {
#pragma unroll
        for (int ky = 0; ky < 3; ++ky) {
            int yy = py + ky - 1;
            bool rok = (unsigned)yy < 16u;
#pragma unroll
            for (int kx = 0; kx < 3; ++kx) {
                int xx = px + kx - 1;
                uint32_t v = 0;
                if (rok && (unsigned)xx < 16u) v = pb[c * 256 + yy * 16 + xx];
                float f0 = (float)(v & 0xffu), f1 = (float)((v >> 8) & 0xffu);
                float f2 = (float)((v >> 16) & 0xffu), f3 = (float)(v >> 24);
                int t9 = ky * 3 + kx;
#pragma unroll
                for (int oo = 0; oo < 4; ++oo) {
                    float4 w4 = *reinterpret_cast<const float4*>(&w_lds[c][t9][oo * 4]);
                    FMA4(acc[oo * 4 + 0], w4.x);
                    FMA4(acc[oo * 4 + 1], w4.y);
                    FMA4(acc[oo * 4 + 2], w4.z);
                    FMA4(acc[oo * 4 + 3], w4.w);
                }
            }
        }
    }
    size_t zb = (size_t)t4 * 65536 + (size_t)(b * 32 + oh * 16) * 256 + tid;
#pragma unroll
    for (int o = 0; o < 16; ++o) z2p[zb + o * 256] = acc[o];
}

// ---- Wf1 3-way bf16 split: w = h + m + l (RNE at each stage) ----
__device__ __forceinline__ ushort f2bf(float f) {
    uint32_t u = __float_as_uint(f);
    u = u + 0x7fffu + ((u >> 16) & 1u);   // round-to-nearest-even
    return (ushort)(u >> 16);
}
__device__ __forceinline__ float bf2f(ushort h) {
    return __uint_as_float((uint32_t)h << 16);
}
__global__ __launch_bounds__(256) void k_wsplit(const float* __restrict__ W,
                                                ushort* __restrict__ Wh,
                                                ushort* __restrict__ Wm,
                                                ushort* __restrict__ Wl, int n) {
    int i = blockIdx.x * 256 + threadIdx.x;
    if (i >= n) return;
    float w = W[i];
    ushort h = f2bf(w);
    float r1 = w - bf2f(h);
    ushort m = f2bf(r1);
    float r2 = r1 - bf2f(m);
    ushort l = f2bf(r2);
    Wh[i] = h; Wm[i] = m; Wl[i] = l;
}

// ---- SF1 via bf16 MFMA (3-way split weights, exact {0,1} spikes) ----
// wave computes 32o x 16t; block = 4 waves = 64o x 32t.
// grid = (8 o-blocks, 10 t-blocks, 8 b).
__device__ __forceinline__ bf16x8 ldb(const ushort* p) {
    return *reinterpret_cast<const bf16x8*>(p);
}
__global__ __launch_bounds__(256) void k_fc1_mfma(const ushort* __restrict__ Wh,
                                                  const ushort* __restrict__ Wm,
                                                  const ushort* __restrict__ Wl,
                                                  const ushort* __restrict__ sb,
                                                  float* __restrict__ z) {
    int tid = threadIdx.x, lane = tid & 63, wv = tid >> 6;
    int l15 = lane & 15, l4 = lane >> 4;
    int oA = blockIdx.x * 64 + (wv & 1) * 32 + l15;       // A-frag row (f=0)
    int t  = blockIdx.y * 32 + (wv >> 1) * 16 + l15;      // B-frag col / store col
    int b  = blockIdx.z;
    size_t a0 = (size_t)oA * 2048 + l4 * 8;               // f=0
    size_t a1 = a0 + 16 * 2048;                           // f=1
    size_t bo = ((size_t)b * 320 + t) * 2048 + l4 * 8;

    f32x4 acc0 = {0.f, 0.f, 0.f, 0.f};
    f32x4 acc1 = {0.f, 0.f, 0.f, 0.f};

    bf16x8 h0 = ldb(Wh + a0), h1 = ldb(Wh + a1);
    bf16x8 m0 = ldb(Wm + a0), m1 = ldb(Wm + a1);
    bf16x8 l0 = ldb(Wl + a0), l1 = ldb(Wl + a1);
    bf16x8 bb = ldb(sb + bo);

    for (int ks = 0; ks < 64; ++ks) {
        int kn = (ks < 63) ? (ks + 1) * 32 : 0;          // clamp: last prefetch redundant
        bf16x8 nh0 = ldb(Wh + a0 + kn), nh1 = ldb(Wh + a1 + kn);
        bf16x8 nm0 = ldb(Wm + a0 + kn), nm1 = ldb(Wm + a1 + kn);
        bf16x8 nl0 = ldb(Wl + a0 + kn), nl1 = ldb(Wl + a1 + kn);
        bf16x8 nbb = ldb(sb + bo + kn);
        acc0 = __builtin_amdgcn_mfma_f32_16x16x32_bf16(h0, bb, acc0, 0, 0, 0);
        acc1 = __builtin_amdgcn_mfma_f32_16x16x32_bf16(h1, bb, acc1, 0, 0, 0);
        acc0 = __builtin_amdgcn_mfma_f32_16x16x32_bf16(m0, bb, acc0, 0, 0, 0);
        acc1 = __builtin_amdgcn_mfma_f32_16x16x32_bf16(m1, bb, acc1, 0, 0, 0);
        acc0 = __builtin_amdgcn_mfma_f32_16x16x32_bf16(l0, bb, acc0, 0, 0, 0);
        acc1 = __builtin_amdgcn_mfma_f32_16x16x32_bf16(l1, bb, acc1, 0, 0, 0);
        h0 = nh0; h1 = nh1; m0 = nm0; m1 = nm1; l0 = nl0; l1 = nl1; bb = nbb;
    }

    if (t < T_STEPS) {
        int orow = blockIdx.x * 64 + (wv & 1) * 32 + l4 * 4;   // D row = (lane>>4)*4+reg
        float* zr = z + ((size_t)b * 512 + orow) * T_STEPS + t;
        zr[0 * T_STEPS] = acc0.x;  zr[1 * T_STEPS] = acc0.y;
        zr[2 * T_STEPS] = acc0.z;  zr[3 * T_STEPS] = acc0.w;
        float* zr2 = zr + 16 * T_STEPS;
        zr2[0 * T_STEPS] = acc1.x; zr2[1 * T_STEPS] = acc1.y;
        zr2[2 * T_STEPS] = acc1.z; zr2[3 * T_STEPS] = acc1.w;
    }
}

// ---- SF2: 512 -> 11 FC (t-major f32 spikes) ----
__global__ __launch_bounds__(256) void k_fc2(const float* __restrict__ s5,
                                             const float* __restrict__ Wf2,
                                             float* __restrict__ z) {
    int idx = blockIdx.x * 256 + threadIdx.x;   // 11*8*75 = 6600
    if (idx >= 6600) return;
    int t4 = idx % T4;
    int r  = idx / T4;            // o*8 + b
    int b = r & 7, o = r >> 3;
    const float* sp = s5 + (size_t)b * 512 * T_STEPS + 4 * t4;
    const float* wp = Wf2 + (size_t)o * 512;
    float a0 = 0.f, a1 = 0.f, a2 = 0.f, a3 = 0.f;
#pragma unroll 2
    for (int k = 0; k < 512; k += 4) {
        float4 wv = *reinterpret_cast<const float4*>(wp + k);
        float4 v0 = *reinterpret_cast<const float4*>(sp + (size_t)(k + 0) * T_STEPS);
        float4 v1 = *reinterpret_cast<const float4*>(sp + (size_t)(k + 1) * T_STEPS);
        float4 v2 = *reinterpret_cast<const float4*>(sp + (size_t)(k + 2) * T_STEPS);
        float4 v3 = *reinterpret_cast<const float4*>(sp + (size_t)(k + 3) * T_STEPS);
        a0 = fmaf(wv.x, v0.x, a0); a1 = fmaf(wv.x, v0.y, a1); a2 = fmaf(wv.x, v0.z, a2); a3 = fmaf(wv.x, v0.w, a3);
        a0 = fmaf(wv.y, v1.x, a0); a1 = fmaf(wv.y, v1.y, a1); a2 = fmaf(wv.y, v1.z, a2); a3 = fmaf(wv.y, v1.w, a3);
        a0 = fmaf(wv.z, v2.x, a0); a1 = fmaf(wv.z, v2.y, a1); a2 = fmaf(wv.z, v2.z, a2); a3 = fmaf(wv.z, v2.w, a3);
        a0 = fmaf(wv.w, v3.x, a0); a1 = fmaf(wv.w, v3.y, a1); a2 = fmaf(wv.w, v3.z, a2); a3 = fmaf(wv.w, v3.w, a3);
    }
    *reinterpret_cast<float4*>(z + (size_t)(b * 11 + o) * T_STEPS + 4 * t4) = make_float4(a0, a1, a2, a3);
}

__global__ void k_zero(float* out, int n) {
    int i = blockIdx.x * 256 + threadIdx.x;
    if (i < n) out[i] = 0.f;
}

extern "C" void kernel_launch(void* const* d_in, const int* in_sizes, int n_in,
                              void* d_out, int out_size, void* d_ws, size_t ws_size,
                              hipStream_t stream) {
    const float* s_in = (const float*)d_in[0];
    const float* W1   = (const float*)d_in[1];
    const float* W2   = (const float*)d_in[2];
    const float* Wf1  = (const float*)d_in[3];
    const float* Wf2  = (const float*)d_in[4];
    float* out = (float*)d_out;

    // workspace layout (bytes); Z region reused by every stage's membrane drive
    const size_t OFF_Z  = 0;               // max 157,286,400 (conv1 z planes)
    const size_t OFF_S0 = 157286400;       // u32 planes,  4,915,200
    const size_t OFF_S1 = 162201600;       // u32 planes, 39,321,600
    const size_t OFF_S2 = 201523200;       // u32 planes,  9,830,400
    const size_t OFF_S3 = 211353600;       // u32 planes, 19,660,800
    const size_t OFF_SB = 231014400;       // bf16 [8][320][2048] = 10,485,760
    const size_t OFF_S5 = 241500160;       // f32 t-major, 4,915,200
    const size_t OFF_WH = 246415360;       // bf16 512x2048 = 2,097,152
    const size_t OFF_WM = 248512512;
    const size_t OFF_WL = 250609664;
    const size_t NEEDED = 252706816;

    if (ws_size < NEEDED) {
        k_zero<<<(26400 + 255) / 256, 256, 0, stream>>>(out, 26400);
        return;
    }

    char* ws = (char*)d_ws;
    float*    Z   = (float*)(ws + OFF_Z);
    uint32_t* s0p = (uint32_t*)(ws + OFF_S0);
    uint32_t* s1p = (uint32_t*)(ws + OFF_S1);
    uint32_t* s2p = (uint32_t*)(ws + OFF_S2);
    uint32_t* s3p = (uint32_t*)(ws + OFF_S3);
    ushort*   sbf = (ushort*)(ws + OFF_SB);
    float*    s5  = (float*)(ws + OFF_S5);
    ushort*   Wh  = (ushort*)(ws + OFF_WH);
    ushort*   Wm  = (ushort*)(ws + OFF_WM);
    ushort*   Wl  = (ushort*)(ws + OFF_WL);

    // Wf1 split (independent of the pipeline; 1M elems)
    k_wsplit<<<4096, 256, 0, stream>>>(Wf1, Wh, Wm, Wl, 512 * 2048);

    // SP0: pool4 (t-major z) + scan -> u32 planes
    k_pool4<<<4800, 256, 0, stream>>>(s_in, Z);
    k_scan_l0<<<64, 256, 0, stream>>>(Z, s0p, 16384);

    // SC1: conv 5x5 (2->16), all-o-in-regs -> z planes; scan -> s1p
    k_conv1<<<2400, 256, 0, stream>>>(s0p, W1, (float4*)Z);
    k_scan_plane<<<512, 256, 0, stream>>>((const float4*)Z, s1p, 131072);

    // SP1: fused pool2+scan (32x32 -> 16x16, 128 bc)
    k_pool2s<16, 131072, 32768><<<128, 256, 0, stream>>>(s1p, s2p);

    // SC2: conv 3x3 (16->32), 16-o halves -> z planes; scan -> s3p
    k_conv2<<<1200, 256, 0, stream>>>(s2p, W2, (float4*)Z);
    k_scan_plane<<<256, 256, 0, stream>>>((const float4*)Z, s3p, 65536);

    // SP2: fused pool2+scan -> k-major bf16 spikes [b][320][2048]
    k_pool2s_bf<<<64, 256, 0, stream>>>(s3p, sbf);

    // SF1: bf16-MFMA GEMM (3-split) -> t-major z; scan -> s5
    k_fc1_mfma<<<dim3(8, 10, 8), 256, 0, stream>>>(Wh, Wm, Wl, sbf, Z);
    k_scan_f32<<<16, 256, 0, stream>>>(Z, s5, 4096, 300);

    // SF2: FC 512->11 + final scan into d_out
    k_fc2<<<26, 256, 0, stream>>>(s5, Wf2, Z);
    k_scan_f32<<<1, 128, 0, stream>>>(Z, out, 88, 300);
}

// Round 6
// 988.491 us; speedup vs baseline: 1.0012x; 1.0012x over previous
//
#include <hip/hip_runtime.h>
#include <stdint.h>

#define T_STEPS 300
#define T4 75

typedef __attribute__((ext_vector_type(8))) short bf16x8;
typedef __attribute__((ext_vector_type(4))) float f32x4;

// ---- scan (psp + spike) constants: d = exp(-1), c = e, cr = -2*theta*e ----
__device__ __forceinline__ void scan_step(float x, float& pp, float& pq,
                                          float& rp, float& rq, float& s_out) {
    const float D  = 0.36787944117144233f;
    const float C  = 2.7182818284590452f;
    const float CR = -54.365636569180904f;
    const float TH = 10.0f;
    pq = D * (pq + pp);      // psp state (q uses old p)
    pp = D * pp + x;
    float u = C * pq;
    rq = D * (rq + rp);      // refractory state
    float s = (u + CR * rq >= TH) ? 1.0f : 0.0f;
    rp = D * rp + s;
    s_out = s;
}

#define SCAN4(v, PACK)                                                     \
    {                                                                      \
        float s0, s1, s2, s3;                                              \
        scan_step(v.x, pp, pq, rp, rq, s0);                                \
        scan_step(v.y, pp, pq, rp, rq, s1);                                \
        scan_step(v.z, pp, pq, rp, rq, s2);                                \
        scan_step(v.w, pp, pq, rp, rq, s3);                                \
        PACK = (uint32_t)s0 | ((uint32_t)s1 << 8) |                        \
               ((uint32_t)s2 << 16) | ((uint32_t)s3 << 24);                \
    }

#define FMA4(A, wc) A.x = fmaf(wc, f0, A.x); A.y = fmaf(wc, f1, A.y); \
                    A.z = fmaf(wc, f2, A.z); A.w = fmaf(wc, f3, A.w);

// ---- SP0 spatial: 4x4 sum-pool * 11 on raw input (t-major z out) ----
__global__ __launch_bounds__(256) void k_pool4(const float* __restrict__ in,
                                               float* __restrict__ z) {
    int idx = blockIdx.x * 256 + threadIdx.x;   // 16384 * 75
    int t4 = idx % T4;
    int n  = idx / T4;                // (b*2+c)*1024 + y*32 + x
    int x = n & 31, y = (n >> 5) & 31, bc = n >> 10;
    const float* base = in + ((size_t)bc * 16384 + (size_t)(4 * y) * 128 + 4 * x) * T_STEPS + 4 * t4;
    float4 acc = {0.f, 0.f, 0.f, 0.f};
#pragma unroll
    for (int i = 0; i < 4; ++i)
#pragma unroll
        for (int j = 0; j < 4; ++j) {
            float4 v = *reinterpret_cast<const float4*>(base + ((size_t)i * 128 + j) * T_STEPS);
            acc.x += v.x; acc.y += v.y; acc.z += v.z; acc.w += v.w;
        }
    float4 o = {11.f * acc.x, 11.f * acc.y, 11.f * acc.z, 11.f * acc.w};
    *reinterpret_cast<float4*>(z + (size_t)n * T_STEPS + 4 * t4) = o;
}

// ---- scan: t-major f32 z in -> u32 spike planes out ----
__global__ __launch_bounds__(256) void k_scan_l0(const float* __restrict__ z,
                                                 uint32_t* __restrict__ sp, int N) {
    int n = blockIdx.x * 256 + threadIdx.x;
    if (n >= N) return;
    const float4* zp = reinterpret_cast<const float4*>(z + (size_t)n * T_STEPS);
    float pp = 0.f, pq = 0.f, rp = 0.f, rq = 0.f;
#pragma unroll 2
    for (int t4 = 0; t4 < T4; ++t4) {
        float4 v = zp[t4];
        uint32_t pack;
        SCAN4(v, pack);
        sp[(size_t)t4 * N + n] = pack;
    }
}

// ---- scan: f4 z planes in -> u32 spike planes out ----
__global__ __launch_bounds__(256) void k_scan_plane(const float4* __restrict__ z,
                                                    uint32_t* __restrict__ sp, int N) {
    int n = blockIdx.x * 256 + threadIdx.x;
    if (n >= N) return;
    float pp = 0.f, pq = 0.f, rp = 0.f, rq = 0.f;
#pragma unroll 2
    for (int t4 = 0; t4 < T4; ++t4) {
        float4 v = z[(size_t)t4 * N + n];
        uint32_t pack;
        SCAN4(v, pack);
        sp[(size_t)t4 * N + n] = pack;
    }
}

// ---- scan: t-major f32 z in -> t-major f32 spikes out (FC tail) ----
__global__ __launch_bounds__(256) void k_scan_f32(const float* __restrict__ z,
                                                  float* __restrict__ s, int N, int ostride) {
    int n = blockIdx.x * blockDim.x + threadIdx.x;
    if (n >= N) return;
    const float4* zp = reinterpret_cast<const float4*>(z + (size_t)n * T_STEPS);
    float* spo = s + (size_t)n * ostride;
    float pp = 0.f, pq = 0.f, rp = 0.f, rq = 0.f;
    for (int it = 0; it < T4; ++it) {
        float4 v = zp[it];
        float4 o;
        scan_step(v.x, pp, pq, rp, rq, o.x);
        scan_step(v.y, pp, pq, rp, rq, o.y);
        scan_step(v.z, pp, pq, rp, rq, o.z);
        scan_step(v.w, pp, pq, rp, rq, o.w);
        *reinterpret_cast<float4*>(spo + it * 4) = o;
    }
}

// ---- fused 2x2 sum-pool * 11 + scan on u32 spike planes (SP1) ----
template<int HW, int NIN, int NOUT>
__global__ __launch_bounds__(256) void k_pool2s(const uint32_t* __restrict__ sin,
                                                uint32_t* __restrict__ sout) {
    int n = blockIdx.x * 256 + threadIdx.x;
    if (n >= NOUT) return;
    int x = n % HW, y = (n / HW) % HW, bc = n / (HW * HW);
    const int W2d = HW * 2;
    const uint32_t* base0 = sin + (size_t)bc * W2d * W2d + (size_t)(2 * y) * W2d + 2 * x;
    float pp = 0.f, pq = 0.f, rp = 0.f, rq = 0.f;
#pragma unroll 2
    for (int t4 = 0; t4 < T4; ++t4) {
        const uint32_t* p = base0 + (size_t)t4 * NIN;
        uint32_t sum = p[0] + p[1] + p[W2d] + p[W2d + 1];  // SWAR, bytes <= 4
        float4 v;
        v.x = 11.f * (float)(sum & 0xffu);
        v.y = 11.f * (float)((sum >> 8) & 0xffu);
        v.z = 11.f * (float)((sum >> 16) & 0xffu);
        v.w = 11.f * (float)(sum >> 24);
        uint32_t pack;
        SCAN4(v, pack);
        sout[(size_t)t4 * NOUT + n] = pack;
    }
}

// ---- SP2: fused 2x2 pool + scan, emits k-major bf16 spikes [b][t_pad=320][2048] ----
__global__ __launch_bounds__(256) void k_pool2s_bf(const uint32_t* __restrict__ sin,
                                                   ushort* __restrict__ sb) {
    int n = blockIdx.x * 256 + threadIdx.x;   // 16384 = b*2048 + k (k = c*64+y*8+x)
    if (n >= 16384) return;
    int x = n & 7, y = (n >> 3) & 7, bc = n >> 6;
    const uint32_t* base0 = sin + (size_t)bc * 256 + (size_t)(2 * y) * 16 + 2 * x;
    int b = n >> 11, k = n & 2047;
    ushort* out = sb + (size_t)b * 320 * 2048 + k;
    float pp = 0.f, pq = 0.f, rp = 0.f, rq = 0.f;
    for (int t4 = 0; t4 < T4; ++t4) {
        const uint32_t* p = base0 + (size_t)t4 * 65536;
        uint32_t sum = p[0] + p[1] + p[16] + p[17];
        float4 v;
        v.x = 11.f * (float)(sum & 0xffu);
        v.y = 11.f * (float)((sum >> 8) & 0xffu);
        v.z = 11.f * (float)((sum >> 16) & 0xffu);
        v.w = 11.f * (float)(sum >> 24);
        float s0, s1, s2, s3;
        scan_step(v.x, pp, pq, rp, rq, s0);
        scan_step(v.y, pp, pq, rp, rq, s1);
        scan_step(v.z, pp, pq, rp, rq, s2);
        scan_step(v.w, pp, pq, rp, rq, s3);
        out[(size_t)(t4 * 4 + 0) * 2048] = s0 != 0.f ? 0x3F80 : 0;
        out[(size_t)(t4 * 4 + 1) * 2048] = s1 != 0.f ? 0x3F80 : 0;
        out[(size_t)(t4 * 4 + 2) * 2048] = s2 != 0.f ? 0x3F80 : 0;
        out[(size_t)(t4 * 4 + 3) * 2048] = s3 != 0.f ? 0x3F80 : 0;
    }
}

// ---- SC1: 5x5 conv 2->16 over 32x32; thread = (b,pix,t4), ALL 16 o in regs ----
__global__ __launch_bounds__(256) void k_conv1(const uint32_t* __restrict__ s0p,
                                               const float* __restrict__ W1,
                                               float4* __restrict__ z1p) {
    __shared__ float w_lds[2][25][16];
    int bid = blockIdx.x;               // 2400
    int pixblk = bid & 3;
    int t4 = (bid >> 2) % 75;
    int b  = bid / 300;
    int tid = threadIdx.x;
    for (int j = tid; j < 800; j += 256) {
        int o = j & 15, kk = (j >> 4) % 25, c = j / 400;
        w_lds[c][kk][o] = W1[(o * 2 + c) * 25 + kk];
    }
    __syncthreads();
    int pix = pixblk * 256 + tid;
    int px = pix & 31, py = pix >> 5;
    float4 acc[16];
#pragma unroll
    for (int o = 0; o < 16; ++o) acc[o] = make_float4(0.f, 0.f, 0.f, 0.f);
    const uint32_t* pb = s0p + (size_t)t4 * 16384 + (size_t)(b * 2) * 1024;
    for (int c = 0; c < 2; ++c) {
#pragma unroll
        for (int ky = 0; ky < 5; ++ky) {
            int yy = py + ky - 2;
            bool rok = (unsigned)yy < 32u;
#pragma unroll
            for (int kx = 0; kx < 5; ++kx) {
                int xx = px + kx - 2;
                uint32_t v = 0;
                if (rok && (unsigned)xx < 32u) v = pb[c * 1024 + yy * 32 + xx];
                float f0 = (float)(v & 0xffu), f1 = (float)((v >> 8) & 0xffu);
                float f2 = (float)((v >> 16) & 0xffu), f3 = (float)(v >> 24);
                int kk = ky * 5 + kx;
#pragma unroll
                for (int oo = 0; oo < 4; ++oo) {
                    float4 w4 = *reinterpret_cast<const float4*>(&w_lds[c][kk][oo * 4]);
                    FMA4(acc[oo * 4 + 0], w4.x);
                    FMA4(acc[oo * 4 + 1], w4.y);
                    FMA4(acc[oo * 4 + 2], w4.z);
                    FMA4(acc[oo * 4 + 3], w4.w);
                }
            }
        }
    }
    size_t zb = (size_t)t4 * 131072 + (size_t)(b * 16) * 1024 + pix;
#pragma unroll
    for (int o = 0; o < 16; ++o) z1p[zb + o * 1024] = acc[o];
}

// ---- SC2: 3x3 conv 16->32 over 16x16; thread = (b,pix,t4), 16 o per half ----
__global__ __launch_bounds__(256) void k_conv2(const uint32_t* __restrict__ s2p,
                                               const float* __restrict__ W2,
                                               float4* __restrict__ z2p) {
    __shared__ float w_lds[16][9][16];
    int bid = blockIdx.x;               // 1200
    int oh = bid & 1;
    int t4 = (bid >> 1) % 75;
    int b  = bid / 150;
    int tid = threadIdx.x;              // pix (16x16)
    for (int j = tid; j < 2304; j += 256) {
        int o = j & 15;
        int t9 = (j >> 4) % 9;
        int c  = j / 144;
        w_lds[c][t9][o] = W2[(size_t)((oh * 16 + o) * 16 + c) * 9 + t9];
    }
    __syncthreads();
    int px = tid & 15, py = tid >> 4;
    float4 acc[16];
#pragma unroll
    for (int o = 0; o < 16; ++o) acc[o] = make_float4(0.f, 0.f, 0.f, 0.f);
    const uint32_t* pb = s2p + (size_t)t4 * 32768 + (size_t)(b * 16) * 256;
    for (int c = 0; c < 16; ++c) {
#pragma unroll
        for (int ky = 0; ky < 3; ++ky) {
            int yy = py + ky - 1;
            bool rok = (unsigned)yy < 16u;
#pragma unroll
            for (int kx = 0; kx < 3; ++kx) {
                int xx = px + kx - 1;
                uint32_t v = 0;
                if (rok && (unsigned)xx < 16u) v = pb[c * 256 + yy * 16 + xx];
                float f0 = (float)(v & 0xffu), f1 = (float)((v >> 8) & 0xffu);
                float f2 = (float)((v >> 16) & 0xffu), f3 = (float)(v >> 24);
                int t9 = ky * 3 + kx;
#pragma unroll
                for (int oo = 0; oo < 4; ++oo) {
                    float4 w4 = *reinterpret_cast<const float4*>(&w_lds[c][t9][oo * 4]);
                    FMA4(acc[oo * 4 + 0], w4.x);
                    FMA4(acc[oo * 4 + 1], w4.y);
                    FMA4(acc[oo * 4 + 2], w4.z);
                    FMA4(acc[oo * 4 + 3], w4.w);
                }
            }
        }
    }
    size_t zb = (size_t)t4 * 65536 + (size_t)(b * 32 + oh * 16) * 256 + tid;
#pragma unroll
    for (int o = 0; o < 16; ++o) z2p[zb + o * 256] = acc[o];
}

// ---- Wf1 3-way bf16 split: w = h + m + l (RNE at each stage) ----
__device__ __forceinline__ ushort f2bf(float f) {
    uint32_t u = __float_as_uint(f);
    u = u + 0x7fffu + ((u >> 16) & 1u);   // round-to-nearest-even
    return (ushort)(u >> 16);
}
__device__ __forceinline__ float bf2f(ushort h) {
    return __uint_as_float((uint32_t)h << 16);
}
__global__ __launch_bounds__(256) void k_wsplit(const float* __restrict__ W,
                                                ushort* __restrict__ Wh,
                                                ushort* __restrict__ Wm,
                                                ushort* __restrict__ Wl, int n) {
    int i = blockIdx.x * 256 + threadIdx.x;
    if (i >= n) return;
    float w = W[i];
    ushort h = f2bf(w);
    float r1 = w - bf2f(h);
    ushort m = f2bf(r1);
    float r2 = r1 - bf2f(m);
    ushort l = f2bf(r2);
    Wh[i] = h; Wm[i] = m; Wl[i] = l;
}

// ---- SF1 via bf16 MFMA (3-way split weights, exact {0,1} spikes) ----
// wave computes 32o x 16t; block = 4 waves = 64o x 32t.
// Flat grid 640: o_tile = bid & 7 pins each o-tile to one XCD (round-robin
// block->XCD dispatch), so that tile's W working set (786 KB bf16 x3) stays
// L2-resident instead of every XCD thrashing all 16 MB.
__device__ __forceinline__ bf16x8 ldb(const ushort* p) {
    return *reinterpret_cast<const bf16x8*>(p);
}
__global__ __launch_bounds__(256) void k_fc1_mfma(const ushort* __restrict__ Wh,
                                                  const ushort* __restrict__ Wm,
                                                  const ushort* __restrict__ Wl,
                                                  const ushort* __restrict__ sb,
                                                  float* __restrict__ z) {
    int bid = blockIdx.x;               // 640
    int obk = bid & 7;                  // XCD-pinned o-tile
    int r   = bid >> 3;                 // 0..79
    int tbk = r % 10;
    int b   = r / 10;
    int tid = threadIdx.x, lane = tid & 63, wv = tid >> 6;
    int l15 = lane & 15, l4 = lane >> 4;
    int oA = obk * 64 + (wv & 1) * 32 + l15;              // A-frag row (f=0)
    int t  = tbk * 32 + (wv >> 1) * 16 + l15;             // B-frag col / store col
    size_t a0 = (size_t)oA * 2048 + l4 * 8;               // f=0
    size_t a1 = a0 + 16 * 2048;                           // f=1
    size_t bo = ((size_t)b * 320 + t) * 2048 + l4 * 8;

    f32x4 acc0 = {0.f, 0.f, 0.f, 0.f};
    f32x4 acc1 = {0.f, 0.f, 0.f, 0.f};

    bf16x8 h0 = ldb(Wh + a0), h1 = ldb(Wh + a1);
    bf16x8 m0 = ldb(Wm + a0), m1 = ldb(Wm + a1);
    bf16x8 l0 = ldb(Wl + a0), l1 = ldb(Wl + a1);
    bf16x8 bb = ldb(sb + bo);

    for (int ks = 0; ks < 64; ++ks) {
        int kn = (ks < 63) ? (ks + 1) * 32 : 0;          // clamp: last prefetch redundant
        bf16x8 nh0 = ldb(Wh + a0 + kn), nh1 = ldb(Wh + a1 + kn);
        bf16x8 nm0 = ldb(Wm + a0 + kn), nm1 = ldb(Wm + a1 + kn);
        bf16x8 nl0 = ldb(Wl + a0 + kn), nl1 = ldb(Wl + a1 + kn);
        bf16x8 nbb = ldb(sb + bo + kn);
        acc0 = __builtin_amdgcn_mfma_f32_16x16x32_bf16(h0, bb, acc0, 0, 0, 0);
        acc1 = __builtin_amdgcn_mfma_f32_16x16x32_bf16(h1, bb, acc1, 0, 0, 0);
        acc0 = __builtin_amdgcn_mfma_f32_16x16x32_bf16(m0, bb, acc0, 0, 0, 0);
        acc1 = __builtin_amdgcn_mfma_f32_16x16x32_bf16(m1, bb, acc1, 0, 0, 0);
        acc0 = __builtin_amdgcn_mfma_f32_16x16x32_bf16(l0, bb, acc0, 0, 0, 0);
        acc1 = __builtin_amdgcn_mfma_f32_16x16x32_bf16(l1, bb, acc1, 0, 0, 0);
        h0 = nh0; h1 = nh1; m0 = nm0; m1 = nm1; l0 = nl0; l1 = nl1; bb = nbb;
    }

    if (t < T_STEPS) {
        int orow = obk * 64 + (wv & 1) * 32 + l4 * 4;     // D row = (lane>>4)*4+reg
        float* zr = z + ((size_t)b * 512 + orow) * T_STEPS + t;
        zr[0 * T_STEPS] = acc0.x;  zr[1 * T_STEPS] = acc0.y;
        zr[2 * T_STEPS] = acc0.z;  zr[3 * T_STEPS] = acc0.w;
        float* zr2 = zr + 16 * T_STEPS;
        zr2[0 * T_STEPS] = acc1.x; zr2[1 * T_STEPS] = acc1.y;
        zr2[2 * T_STEPS] = acc1.z; zr2[3 * T_STEPS] = acc1.w;
    }
}

// ---- SF2: 512 -> 11 FC (t-major f32 spikes) ----
__global__ __launch_bounds__(256) void k_fc2(const float* __restrict__ s5,
                                             const float* __restrict__ Wf2,
                                             float* __restrict__ z) {
    int idx = blockIdx.x * 256 + threadIdx.x;   // 11*8*75 = 6600
    if (idx >= 6600) return;
    int t4 = idx % T4;
    int r  = idx / T4;            // o*8 + b
    int b = r & 7, o = r >> 3;
    const float* sp = s5 + (size_t)b * 512 * T_STEPS + 4 * t4;
    const float* wp = Wf2 + (size_t)o * 512;
    float a0 = 0.f, a1 = 0.f, a2 = 0.f, a3 = 0.f;
#pragma unroll 2
    for (int k = 0; k < 512; k += 4) {
        float4 wv = *reinterpret_cast<const float4*>(wp + k);
        float4 v0 = *reinterpret_cast<const float4*>(sp + (size_t)(k + 0) * T_STEPS);
        float4 v1 = *reinterpret_cast<const float4*>(sp + (size_t)(k + 1) * T_STEPS);
        float4 v2 = *reinterpret_cast<const float4*>(sp + (size_t)(k + 2) * T_STEPS);
        float4 v3 = *reinterpret_cast<const float4*>(sp + (size_t)(k + 3) * T_STEPS);
        a0 = fmaf(wv.x, v0.x, a0); a1 = fmaf(wv.x, v0.y, a1); a2 = fmaf(wv.x, v0.z, a2); a3 = fmaf(wv.x, v0.w, a3);
        a0 = fmaf(wv.y, v1.x, a0); a1 = fmaf(wv.y, v1.y, a1); a2 = fmaf(wv.y, v1.z, a2); a3 = fmaf(wv.y, v1.w, a3);
        a0 = fmaf(wv.z, v2.x, a0); a1 = fmaf(wv.z, v2.y, a1); a2 = fmaf(wv.z, v2.z, a2); a3 = fmaf(wv.z, v2.w, a3);
        a0 = fmaf(wv.w, v3.x, a0); a1 = fmaf(wv.w, v3.y, a1); a2 = fmaf(wv.w, v3.z, a2); a3 = fmaf(wv.w, v3.w, a3);
    }
    *reinterpret_cast<float4*>(z + (size_t)(b * 11 + o) * T_STEPS + 4 * t4) = make_float4(a0, a1, a2, a3);
}

__global__ void k_zero(float* out, int n) {
    int i = blockIdx.x * 256 + threadIdx.x;
    if (i < n) out[i] = 0.f;
}

extern "C" void kernel_launch(void* const* d_in, const int* in_sizes, int n_in,
                              void* d_out, int out_size, void* d_ws, size_t ws_size,
                              hipStream_t stream) {
    const float* s_in = (const float*)d_in[0];
    const float* W1   = (const float*)d_in[1];
    const float* W2   = (const float*)d_in[2];
    const float* Wf1  = (const float*)d_in[3];
    const float* Wf2  = (const float*)d_in[4];
    float* out = (float*)d_out;

    // workspace layout (bytes); Z region reused by every stage's membrane drive
    const size_t OFF_Z  = 0;               // max 157,286,400 (conv1 z planes)
    const size_t OFF_S0 = 157286400;       // u32 planes,  4,915,200
    const size_t OFF_S1 = 162201600;       // u32 planes, 39,321,600
    const size_t OFF_S2 = 201523200;       // u32 planes,  9,830,400
    const size_t OFF_S3 = 211353600;       // u32 planes, 19,660,800
    const size_t OFF_SB = 231014400;       // bf16 [8][320][2048] = 10,485,760
    const size_t OFF_S5 = 241500160;       // f32 t-major, 4,915,200
    const size_t OFF_WH = 246415360;       // bf16 512x2048 = 2,097,152
    const size_t OFF_WM = 248512512;
    const size_t OFF_WL = 250609664;
    const size_t NEEDED = 252706816;

    if (ws_size < NEEDED) {
        k_zero<<<(26400 + 255) / 256, 256, 0, stream>>>(out, 26400);
        return;
    }

    char* ws = (char*)d_ws;
    float*    Z   = (float*)(ws + OFF_Z);
    uint32_t* s0p = (uint32_t*)(ws + OFF_S0);
    uint32_t* s1p = (uint32_t*)(ws + OFF_S1);
    uint32_t* s2p = (uint32_t*)(ws + OFF_S2);
    uint32_t* s3p = (uint32_t*)(ws + OFF_S3);
    ushort*   sbf = (ushort*)(ws + OFF_SB);
    float*    s5  = (float*)(ws + OFF_S5);
    ushort*   Wh  = (ushort*)(ws + OFF_WH);
    ushort*   Wm  = (ushort*)(ws + OFF_WM);
    ushort*   Wl  = (ushort*)(ws + OFF_WL);

    // Wf1 split (independent of the pipeline; 1M elems)
    k_wsplit<<<4096, 256, 0, stream>>>(Wf1, Wh, Wm, Wl, 512 * 2048);

    // SP0: pool4 (t-major z) + scan -> u32 planes
    k_pool4<<<4800, 256, 0, stream>>>(s_in, Z);
    k_scan_l0<<<64, 256, 0, stream>>>(Z, s0p, 16384);

    // SC1: conv 5x5 (2->16), all-o-in-regs -> z planes; scan -> s1p
    k_conv1<<<2400, 256, 0, stream>>>(s0p, W1, (float4*)Z);
    k_scan_plane<<<512, 256, 0, stream>>>((const float4*)Z, s1p, 131072);

    // SP1: fused pool2+scan (32x32 -> 16x16, 128 bc)
    k_pool2s<16, 131072, 32768><<<128, 256, 0, stream>>>(s1p, s2p);

    // SC2: conv 3x3 (16->32), 16-o halves -> z planes; scan -> s3p
    k_conv2<<<1200, 256, 0, stream>>>(s2p, W2, (float4*)Z);
    k_scan_plane<<<256, 256, 0, stream>>>((const float4*)Z, s3p, 65536);

    // SP2: fused pool2+scan -> k-major bf16 spikes [b][320][2048]
    k_pool2s_bf<<<64, 256, 0, stream>>>(s3p, sbf);

    // SF1: bf16-MFMA GEMM (3-split, XCD-pinned o-tiles) -> t-major z; scan -> s5
    k_fc1_mfma<<<640, 256, 0, stream>>>(Wh, Wm, Wl, sbf, Z);
    k_scan_f32<<<16, 256, 0, stream>>>(Z, s5, 4096, 300);

    // SF2: FC 512->11 + final scan into d_out
    k_fc2<<<26, 256, 0, stream>>>(s5, Wf2, Z);
    k_scan_f32<<<1, 128, 0, stream>>>(Z, out, 88, 300);
}